// Round 1
// baseline (453.795 us; speedup 1.0000x reference)
//
#include <hip/hip_runtime.h>
#include <cstdint>
#include <cstddef>

#define S_NUM 100000
#define T_NUM 20000
#define E_NUM 1000000

typedef __bf16 bf16x8 __attribute__((ext_vector_type(8)));
typedef float f32x4 __attribute__((ext_vector_type(4)));

__device__ __forceinline__ unsigned short f2bf(float f) {
  unsigned int u = __float_as_uint(f);
  u += 0x7fffu + ((u >> 16) & 1u);   // round-to-nearest-even
  return (unsigned short)(u >> 16);
}
__device__ __forceinline__ float bflo(unsigned int v) { return __uint_as_float(v << 16); }
__device__ __forceinline__ float bfhi(unsigned int v) { return __uint_as_float(v & 0xffff0000u); }

// K0: embed [256,128] f32 -> embT [128 n][256 k] bf16 (transposed for B-operand staging)
__global__ void k0_prep(const float* __restrict__ embed, unsigned short* __restrict__ embT) {
  int idx = blockIdx.x * blockDim.x + threadIdx.x;  // 0..32767
  int n = idx & 127, k = idx >> 7;
  embT[n * 256 + k] = f2bf(embed[k * 128 + n]);
}

// K1: xb[S,128] bf16 = bf16( (sf[0:S,0:256] @ embed) / xn ).
// Block = 256 thr (4 waves), tile 128 rows x 128 cols, K in 8 chunks of 32.
__launch_bounds__(256)
__global__ void k1_gemm(const float* __restrict__ sf, const float* __restrict__ xn,
                        const unsigned short* __restrict__ embT,
                        unsigned short* __restrict__ xb) {
  __shared__ unsigned short lA[128][40];  // pad 32->40 to break bank stride
  __shared__ unsigned short lB[128][40];  // B^T rows: lB[n][k]
  const int tid = threadIdx.x;
  const int wave = tid >> 6;
  const int lane = tid & 63;
  const int quad = lane >> 4;
  const int l15 = lane & 15;
  const int row0 = blockIdx.x * 128;

  f32x4 acc[8][2];
#pragma unroll
  for (int i = 0; i < 8; ++i)
#pragma unroll
    for (int j = 0; j < 2; ++j) acc[i][j] = (f32x4){0.f, 0.f, 0.f, 0.f};

  const int ar = tid >> 1;           // 0..127: row handled by this thread
  const int aseg = (tid & 1) * 16;   // which 16-element half of the 32-wide K chunk

  for (int kc = 0; kc < 8; ++kc) {
    const int k0 = kc * 32;
    {  // stage A chunk [128 x 32] f32 -> bf16
      const int gr = row0 + ar;
      float4 v[4];
      if (gr < S_NUM) {
        const float4* p = (const float4*)(sf + (size_t)gr * 256 + k0 + aseg);
        v[0] = p[0]; v[1] = p[1]; v[2] = p[2]; v[3] = p[3];
      } else {
        v[0] = v[1] = v[2] = v[3] = make_float4(0.f, 0.f, 0.f, 0.f);
      }
      unsigned short* dst = &lA[ar][aseg];
#pragma unroll
      for (int i = 0; i < 4; ++i) {
        dst[i * 4 + 0] = f2bf(v[i].x); dst[i * 4 + 1] = f2bf(v[i].y);
        dst[i * 4 + 2] = f2bf(v[i].z); dst[i * 4 + 3] = f2bf(v[i].w);
      }
    }
    {  // stage B^T chunk [128 n x 32 k] bf16 (already transposed+converted by K0)
      const ushort4* p = (const ushort4*)(embT + ar * 256 + k0 + aseg);
      ushort4* dst = (ushort4*)&lA[0][0];  // placeholder to keep types obvious
      (void)dst;
      ushort4* d2 = (ushort4*)&lB[ar][aseg];
      d2[0] = p[0]; d2[1] = p[1]; d2[2] = p[2]; d2[3] = p[3];
    }
    __syncthreads();
    bf16x8 fb[2];
#pragma unroll
    for (int ct = 0; ct < 2; ++ct)
      fb[ct] = *(const bf16x8*)&lB[wave * 32 + ct * 16 + l15][quad * 8];
#pragma unroll
    for (int rt = 0; rt < 8; ++rt) {
      bf16x8 fa = *(const bf16x8*)&lA[rt * 16 + l15][quad * 8];
      acc[rt][0] = __builtin_amdgcn_mfma_f32_16x16x32_bf16(fa, fb[0], acc[rt][0], 0, 0, 0);
      acc[rt][1] = __builtin_amdgcn_mfma_f32_16x16x32_bf16(fa, fb[1], acc[rt][1], 0, 0, 0);
    }
    __syncthreads();
  }
  // epilogue: D col = lane&15, row = quad*4+reg; scale by 1/xn[row], store bf16
  const int col0 = wave * 32;
#pragma unroll
  for (int rt = 0; rt < 8; ++rt) {
#pragma unroll
    for (int reg = 0; reg < 4; ++reg) {
      const int r = row0 + rt * 16 + quad * 4 + reg;
      if (r < S_NUM) {
        const float inv = __builtin_amdgcn_rcpf(xn[r]);
        xb[(size_t)r * 128 + col0 + l15]      = f2bf(acc[rt][0][reg] * inv);
        xb[(size_t)r * 128 + col0 + 16 + l15] = f2bf(acc[rt][1][reg] * inv);
      }
    }
  }
}

// K2: histogram of edge targets
__global__ void k2_count(const int* __restrict__ dst_idx, int* __restrict__ counts) {
  const int stride = gridDim.x * blockDim.x;
  for (int e = blockIdx.x * blockDim.x + threadIdx.x; e < E_NUM; e += stride)
    atomicAdd(&counts[dst_idx[e]], 1);
}

// K3: exclusive scan of counts (T=20000) -> offsets[0..T], cursor copy. One block of 1024.
__global__ void k3_scan(const int* __restrict__ counts, int* __restrict__ offsets,
                        int* __restrict__ cursor) {
  __shared__ int part[1024];
  const int t = threadIdx.x;
  const int base = t * 20;  // 1000 threads x 20 = 20000 exactly
  int s = 0;
  if (t < 1000) {
#pragma unroll
    for (int i = 0; i < 20; ++i) s += counts[base + i];
  }
  part[t] = s;
  __syncthreads();
  for (int off = 1; off < 1024; off <<= 1) {
    int v = part[t];
    int add = (t >= off) ? part[t - off] : 0;
    __syncthreads();
    part[t] = v + add;
    __syncthreads();
  }
  int run = (t == 0) ? 0 : part[t - 1];
  if (t < 1000) {
    for (int i = 0; i < 20; ++i) {
      int c = counts[base + i];
      offsets[base + i] = run;
      cursor[base + i] = run;
      run += c;
    }
  }
  if (t == 0) offsets[T_NUM] = part[1023];
}

// K4: bucket edges by target (counting-sort scatter of src ids)
__global__ void k4_scatter(const int* __restrict__ src_idx, const int* __restrict__ dst_idx,
                           int* __restrict__ cursor, int* __restrict__ ssrc) {
  const int stride = gridDim.x * blockDim.x;
  for (int e = blockIdx.x * blockDim.x + threadIdx.x; e < E_NUM; e += stride) {
    const int d = dst_idx[e];
    const int pos = atomicAdd(&cursor[d], 1);
    ssrc[pos] = src_idx[e];
  }
}

// K5: one wave per target: mean of gathered x rows. Lane holds dims 2*lane, 2*lane+1.
__global__ void k5_aggr(const int* __restrict__ offsets, const int* __restrict__ ssrc,
                        const unsigned short* __restrict__ xb, float* __restrict__ aggr) {
  const int wave = threadIdx.x >> 6, lane = threadIdx.x & 63;
  const int t = blockIdx.x * 4 + wave;  // grid = T/4, exact
  const int beg = offsets[t], end = offsets[t + 1];
  float a0 = 0.f, a1 = 0.f;
  int e = beg;
  for (; e + 1 < end; e += 2) {
    const int s0 = ssrc[e], s1 = ssrc[e + 1];
    const unsigned int v0 = *(const unsigned int*)(xb + (size_t)s0 * 128 + 2 * lane);
    const unsigned int v1 = *(const unsigned int*)(xb + (size_t)s1 * 128 + 2 * lane);
    a0 += bflo(v0); a1 += bfhi(v0);
    a0 += bflo(v1); a1 += bfhi(v1);
  }
  if (e < end) {
    const int s0 = ssrc[e];
    const unsigned int v0 = *(const unsigned int*)(xb + (size_t)s0 * 128 + 2 * lane);
    a0 += bflo(v0); a1 += bfhi(v0);
  }
  const int cnt = end - beg;
  const float inv = (cnt > 0) ? __builtin_amdgcn_rcpf((float)cnt) : 0.f;
  float2 r; r.x = a0 * inv; r.y = a1 * inv;
  *(float2*)(aggr + (size_t)t * 128 + 2 * lane) = r;
}

// K6: out[T,128] = aggr[T,128] @ weight[128,128], fp32 LDS tiles, 16x16 per block
__global__ void k6_out(const float* __restrict__ aggr, const float* __restrict__ W,
                       float* __restrict__ out) {
  __shared__ float lA[16][128];
  __shared__ float lW[128][16];
  const int tid = threadIdx.x;
  const int tx = tid & 15, ty = tid >> 4;
  const int r0 = blockIdx.x * 16, c0 = blockIdx.y * 16;
#pragma unroll
  for (int i = 0; i < 8; ++i) {
    const int idx = i * 256 + tid;
    const int row = idx >> 7, col = idx & 127;
    lA[row][col] = aggr[(size_t)(r0 + row) * 128 + col];
    const int k = idx >> 4, c = idx & 15;
    lW[k][c] = W[(size_t)k * 128 + c0 + c];
  }
  __syncthreads();
  float acc = 0.f;
#pragma unroll
  for (int k = 0; k < 128; ++k) acc += lA[ty][k] * lW[k][tx];
  out[(size_t)(r0 + ty) * 128 + c0 + tx] = acc;
}

extern "C" void kernel_launch(void* const* d_in, const int* in_sizes, int n_in,
                              void* d_out, int out_size, void* d_ws, size_t ws_size,
                              hipStream_t stream) {
  const float* sf      = (const float*)d_in[0];   // [N,256] f32 (only rows < S used)
  const int*   src_idx = (const int*)d_in[1];     // [E]
  const int*   dst_idx = (const int*)d_in[2];     // [E]
  /* d_in[3] range_list: unused */
  const float* xn      = (const float*)d_in[4];   // [N]
  const float* embed   = (const float*)d_in[5];   // [256,128]
  const float* weight  = (const float*)d_in[6];   // [128,128]
  float* out = (float*)d_out;                     // [T,128] f32

  // workspace layout (all 16B-aligned offsets), total ~40.2 MB
  char* w = (char*)d_ws;
  unsigned short* xb   = (unsigned short*)(w);              // S*128*2   = 25,600,000
  unsigned short* embT = (unsigned short*)(w + 25600000);   // 128*256*2 = 65,536
  int* counts  = (int*)(w + 25665536);                      // T*4       = 80,000
  int* offsets = (int*)(w + 25745536);                      // (T+1)*4 -> 80,016 pad
  int* cursor  = (int*)(w + 25825552);                      // T*4       = 80,000
  int* ssrc    = (int*)(w + 25905552);                      // E*4       = 4,000,000
  float* aggr  = (float*)(w + 29905552);                    // T*128*4   = 10,240,000

  hipMemsetAsync(counts, 0, T_NUM * sizeof(int), stream);
  k0_prep<<<128, 256, 0, stream>>>(embed, embT);
  k1_gemm<<<(S_NUM + 127) / 128, 256, 0, stream>>>(sf, xn, embT, xb);
  k2_count<<<1024, 256, 0, stream>>>(dst_idx, counts);
  k3_scan<<<1, 1024, 0, stream>>>(counts, offsets, cursor);
  k4_scatter<<<1024, 256, 0, stream>>>(src_idx, dst_idx, cursor, ssrc);
  k5_aggr<<<T_NUM / 4, 256, 0, stream>>>(offsets, ssrc, xb, aggr);
  k6_out<<<dim3(T_NUM / 16, 8), 256, 0, stream>>>(aggr, weight, out);
}